// Round 4
// baseline (161.355 us; speedup 1.0000x reference)
//
#include <hip/hip_runtime.h>
#include <math.h>

// Problem constants (fixed by setup_inputs)
#define B  4
#define N  512
#define BN (B * N)
#define H  64
#define I  128

#define PI_F   3.14159265358979323846f
#define Y0_F   160.0f
#define Y1_F   155.4930028f   // 160 - 320*(1-1e-5)/71
#define INV_W  (1.0f / 800.0f)

// Fast tanh-GELU: x * sigmoid(2*y), y = x*(c0 + c1*x^2).
// |err vs exact erf-gelu| <= ~3e-3; propagates to <1e-4 at the sigmoid
// output (threshold 1e-2). Verified passing (absmax 0.0) in R3.
__device__ __forceinline__ float gelu_fast(float x) {
    float x2 = x * x;
    float t1 = __builtin_fmaf(x2, -2.0f * 0.0356774081f, -2.0f * 0.7978845608f);
    float e  = __expf(x * t1);                       // exp(-2y)
    return x * __builtin_amdgcn_rcpf(1.0f + e);
}

// ---------------------------------------------------------------------------
// Kernel A: per-node precompute (algebraic collapse of all per-edge matmuls).
//   U[i] = (relu(bf_i@W_cls+b_cls)@W_in + b_in + p_i@W_pos + b_pos)@W_e1 + b_e1
//   V[j] = (relu(bf_j@W_cls+b_cls)@W_out + b_out + p_j@W_pos)@W_e1
//   edge1[b,i,j,:] = U[b,i] - V[b,j]  exactly.
// NEW: nodes with cls < 0.4 are never consumed (column needs cls_j>=0.4,
// row needs cls_i >= cls_j >= 0.4) -> skip them. One node per half-block
// so the skip branch is wave-uniform.
// ---------------------------------------------------------------------------
__global__ __launch_bounds__(256) void prep_kernel(
    const float* __restrict__ bf, const float* __restrict__ cls,
    const float* __restrict__ emb,
    const float* __restrict__ W_cls, const float* __restrict__ b_cls,
    const float* __restrict__ W_pos, const float* __restrict__ b_pos,
    const float* __restrict__ W_in,  const float* __restrict__ b_in,
    const float* __restrict__ W_out, const float* __restrict__ b_out,
    const float* __restrict__ W_e1,  const float* __restrict__ b_e1,
    float* __restrict__ Uo, float* __restrict__ Vo)
{
    __shared__ float sft[2][64];
    __shared__ float su[2][128];
    __shared__ float sv[2][128];
    __shared__ float sp[2][2];

    const int tid   = threadIdx.x;
    const int node0 = blockIdx.x * 2;
    const int nd    = tid >> 7;          // node within block (wave-uniform)
    const int idx   = tid & 127;
    const int gnode = node0 + nd;

    const bool act0 = cls[node0]     >= 0.4f;
    const bool act1 = cls[node0 + 1] >= 0.4f;
    if (!act0 && !act1) return;          // uniform whole-block exit
    const bool act = nd ? act1 : act0;

    // per-node sample points (threads 0,1)
    if (tid < 2) {
        int g = node0 + tid;
        float ang = emb[g * 2] * PI_F;
        float t = tanf(ang);
        float rc = (emb[g * 2 + 1] * 800.0f) / cosf(ang);
        sp[tid][0] = (-t * Y0_F + rc) * INV_W;
        sp[tid][1] = (-t * Y1_F + rc) * INV_W;
    }

    // Stage 1: feats = relu(bf @ W_cls + b_cls), split-k over 2 lanes
    if (act) {
        const int h  = idx >> 1;
        const int kh = idx & 1;           // which 32-d half
        const float* bfp = bf + gnode * 64 + kh * 32;
        float a0 = 0.f, a1 = 0.f, a2 = 0.f, a3 = 0.f;
        #pragma unroll
        for (int d = 0; d < 32; d += 4) {
            int dd = kh * 32 + d;
            a0 += bfp[d + 0] * W_cls[(dd + 0) * 64 + h];
            a1 += bfp[d + 1] * W_cls[(dd + 1) * 64 + h];
            a2 += bfp[d + 2] * W_cls[(dd + 2) * 64 + h];
            a3 += bfp[d + 3] * W_cls[(dd + 3) * 64 + h];
        }
        float a = (a0 + a1) + (a2 + a3);
        a += __shfl_xor(a, 1);
        if (kh == 0) sft[nd][h] = fmaxf(a + b_cls[h], 0.0f);
    }
    __syncthreads();

    // Stage 2: u,v (k = idx), 4 accumulator chains
    if (act) {
        const int k = idx;
        float pe = sp[nd][0] * W_pos[k] + sp[nd][1] * W_pos[128 + k];
        float au0 = 0.f, av0 = 0.f, au1 = 0.f, av1 = 0.f;
        #pragma unroll 8
        for (int h2 = 0; h2 < 64; h2 += 2) {
            float f0 = sft[nd][h2], f1 = sft[nd][h2 + 1];
            au0 += f0 * W_in [h2 * 128 + k];
            av0 += f0 * W_out[h2 * 128 + k];
            au1 += f1 * W_in [(h2 + 1) * 128 + k];
            av1 += f1 * W_out[(h2 + 1) * 128 + k];
        }
        su[nd][k] = (au0 + au1) + b_in[k] + b_pos[k] + pe;
        sv[nd][k] = (av0 + av1) + b_out[k] + pe;
    }
    __syncthreads();

    // Stage 3: U = u@W_e1 + b_e1 ; V = v@W_e1 (k = idx), 4 chains
    if (act) {
        const int k = idx;
        float aU0 = 0.f, aV0 = 0.f, aU1 = 0.f, aV1 = 0.f;
        #pragma unroll 8
        for (int m = 0; m < 128; m += 2) {
            float w0 = W_e1[m * 128 + k];
            float w1 = W_e1[(m + 1) * 128 + k];
            float s0 = su[nd][m], t0 = sv[nd][m];
            float s1 = su[nd][m + 1], t1 = sv[nd][m + 1];
            aU0 += s0 * w0;  aV0 += t0 * w0;
            aU1 += s1 * w1;  aV1 += t1 * w1;
        }
        Uo[gnode * 128 + k] = (aU0 + aU1) + b_e1[k];
        Vo[gnode * 128 + k] = (aV0 + aV1);
    }
}

// ---------------------------------------------------------------------------
// Kernel B: ONE BLOCK PER COLUMN.
// Phase 1: 4 waves mask 512 rows, ballot-compact, stitch into one LDS list.
// Phase 2: each compacted row split across 2 adjacent lanes (64 elems each),
//          combined via shfl_xor(1) -> ~94% lane utilization, half the chain.
// Phase 3: max-reduce -> head MLP on wave 0 -> sigmoid.
// ---------------------------------------------------------------------------
__global__ __launch_bounds__(256) void edge_kernel(
    const float* __restrict__ U, const float* __restrict__ V,
    const float* __restrict__ cls, const int* __restrict__ aid,
    const float* __restrict__ emb,
    const float* __restrict__ W_e2, const float* __restrict__ b_e2,
    const float* __restrict__ W_n1, const float* __restrict__ b_n1,
    const float* __restrict__ W_n2, const float* __restrict__ b_n2,
    const float* __restrict__ W_hd, const float* __restrict__ b_hd,
    float* __restrict__ out)
{
    const int col  = blockIdx.x;          // b*N + j
    const int tid  = threadIdx.x;
    const int wave = tid >> 6;
    const int lane = tid & 63;

    __shared__ float Vs[128];
    __shared__ float w2s[128];
    __shared__ unsigned short lseg[4][128];
    __shared__ unsigned short list[512];
    __shared__ int wcnt[4];
    __shared__ float red[4];
    __shared__ float n1s[64];

    const float cls_j = cls[col];
    if (cls_j < 0.4f) {                   // masked column: sigmoid(-1e6) == 0
        if (tid == 0) out[col] = 0.0f;
        return;                           // uniform: whole block exits
    }

    if (tid < 128) {
        Vs[tid]  = V[col * 128 + tid];
        w2s[tid] = W_e2[tid];
    }

    const int   rowbase = (col >> 9) << 9;   // b*N
    const float ang_j   = emb[col * 2] * PI_F;
    const int   id_j    = aid[col];
    const float be2     = b_e2[0];

    // Phase 1: mask + per-wave ballot compaction (each wave: 128 rows)
    int c = 0;
    #pragma unroll
    for (int rr = 0; rr < 2; ++rr) {
        int i  = wave * 128 + rr * 64 + lane;
        int gi = rowbase + i;
        float ci = cls[gi];
        bool m = (ci > cls_j) || (ci == cls_j && aid[gi] > id_j);
        if (m) m = fabsf(emb[gi * 2] * PI_F - ang_j) < 0.5f;
        unsigned long long bal = __ballot(m);
        int pre = __popcll(bal & ((1ull << lane) - 1ull));
        if (m) lseg[wave][c + pre] = (unsigned short)i;
        c += __popcll(bal);
    }
    if (lane == 0) wcnt[wave] = c;
    __syncthreads();

    const int c0 = wcnt[0], c1 = wcnt[1], c2 = wcnt[2], c3 = wcnt[3];
    const int o1 = c0, o2 = c0 + c1, o3 = o2 + c2;
    const int total = o3 + c3;
    for (int r = tid; r < c0; r += 256) list[r]      = lseg[0][r];
    for (int r = tid; r < c1; r += 256) list[o1 + r] = lseg[1][r];
    for (int r = tid; r < c2; r += 256) list[o2 + r] = lseg[2][r];
    for (int r = tid; r < c3; r += 256) list[o3 + r] = lseg[3][r];
    __syncthreads();

    // Phase 2: item q = 2*row + half; adjacent lanes hold the two halves of
    // one row (q parity), so pairs always iterate together.
    float wm = 0.0f;
    const float4* V4 = (const float4*)Vs;
    const float4* g4 = (const float4*)w2s;
    const int nitems = 2 * total;
    for (int q = tid; q < nitems; q += 256) {
        int r = q >> 1, half = q & 1;
        int gi = rowbase + (int)list[r];
        const float4* Up = (const float4*)(U + gi * 128) + half * 16;
        const float4* Vp = V4 + half * 16;
        const float4* Wp = g4 + half * 16;
        float s0 = 0.f, s1 = 0.f, s2 = 0.f, s3 = 0.f;
        #pragma unroll
        for (int k4 = 0; k4 < 16; ++k4) {
            float4 u4 = Up[k4];
            float4 v4 = Vp[k4];
            float4 w4 = Wp[k4];
            s0 += gelu_fast(u4.x - v4.x) * w4.x;
            s1 += gelu_fast(u4.y - v4.y) * w4.y;
            s2 += gelu_fast(u4.z - v4.z) * w4.z;
            s3 += gelu_fast(u4.w - v4.w) * w4.w;
        }
        float s = (s0 + s1) + (s2 + s3);
        s += __shfl_xor(s, 1);            // combine the two halves
        if (half == 0) wm = fmaxf(wm, s + be2);
    }

    // Phase 3: max-reduce (shuffle within wave, LDS across waves)
    #pragma unroll
    for (int off = 32; off > 0; off >>= 1)
        wm = fmaxf(wm, __shfl_down(wm, off));
    if (lane == 0) red[wave] = wm;
    __syncthreads();

    if (wave == 0) {
        const float nm = fmaxf(fmaxf(red[0], red[1]), fmaxf(red[2], red[3]));
        // head MLP entirely on wave 0 (LDS in-order within a wave)
        n1s[lane] = fmaxf(nm * W_n1[lane] + b_n1[lane], 0.0f);
        float a = b_n2[lane];
        #pragma unroll 8
        for (int m2 = 0; m2 < 64; ++m2) a += n1s[m2] * W_n2[m2 * 64 + lane];
        a = fmaxf(a, 0.0f);
        float p = a * W_hd[lane];
        #pragma unroll
        for (int off = 32; off > 0; off >>= 1) p += __shfl_down(p, off);
        if (lane == 0) {
            float logit = p + b_hd[0];
            out[col] = 1.0f / (1.0f + expf(-logit));
        }
    }
}

extern "C" void kernel_launch(void* const* d_in, const int* in_sizes, int n_in,
                              void* d_out, int out_size, void* d_ws, size_t ws_size,
                              hipStream_t stream) {
    const float* bf    = (const float*)d_in[0];
    const float* cls   = (const float*)d_in[1];
    const int*   aid   = (const int*)  d_in[2];
    const float* emb   = (const float*)d_in[3];
    const float* W_cls = (const float*)d_in[4];
    const float* b_cls = (const float*)d_in[5];
    const float* W_pos = (const float*)d_in[6];
    const float* b_pos = (const float*)d_in[7];
    const float* W_in  = (const float*)d_in[8];
    const float* b_in  = (const float*)d_in[9];
    const float* W_out = (const float*)d_in[10];
    const float* b_out = (const float*)d_in[11];
    const float* W_e1  = (const float*)d_in[12];
    const float* b_e1  = (const float*)d_in[13];
    const float* W_e2  = (const float*)d_in[14];
    const float* b_e2  = (const float*)d_in[15];
    const float* W_n1  = (const float*)d_in[16];
    const float* b_n1  = (const float*)d_in[17];
    const float* W_n2  = (const float*)d_in[18];
    const float* b_n2  = (const float*)d_in[19];
    const float* W_hd  = (const float*)d_in[20];
    const float* b_hd  = (const float*)d_in[21];

    float* Uw = (float*)d_ws;            // [BN,128]
    float* Vw = Uw + BN * I;             // [BN,128]
    float* out = (float*)d_out;

    prep_kernel<<<BN / 2, 256, 0, stream>>>(
        bf, cls, emb, W_cls, b_cls, W_pos, b_pos, W_in, b_in, W_out, b_out,
        W_e1, b_e1, Uw, Vw);
    edge_kernel<<<BN, 256, 0, stream>>>(
        Uw, Vw, cls, aid, emb, W_e2, b_e2, W_n1, b_n1, W_n2, b_n2,
        W_hd, b_hd, out);
}

// Round 5
// 148.988 us; speedup vs baseline: 1.0830x; 1.0830x over previous
//
#include <hip/hip_runtime.h>
#include <math.h>

// Problem constants (fixed by setup_inputs)
#define B  4
#define N  512
#define BN (B * N)
#define H  64
#define I  128

#define PI_F   3.14159265358979323846f
#define Y0_F   160.0f
#define Y1_F   155.4930028f   // 160 - 320*(1-1e-5)/71
#define INV_W  (1.0f / 800.0f)

// Fast tanh-GELU (passed absmax 0.0 in R3/R4 vs 1e-2 threshold).
__device__ __forceinline__ float gelu_fast(float x) {
    float x2 = x * x;
    float t1 = __builtin_fmaf(x2, -2.0f * 0.0356774081f, -2.0f * 0.7978845608f);
    float e  = __expf(x * t1);                       // exp(-2y)
    return x * __builtin_amdgcn_rcpf(1.0f + e);
}

// ---------------------------------------------------------------------------
// Kernel A: per-node precompute (algebraic collapse of all per-edge matmuls).
//   U[i] = (relu(bf_i@W_cls+b_cls)@W_in + b_in + p_i@W_pos + b_pos)@W_e1 + b_e1
//   V[j] = (relu(bf_j@W_cls+b_cls)@W_out + b_out + p_j@W_pos)@W_e1
//   edge1[b,i,j,:] = U[b,i] - V[b,j]  exactly.
// 256 blocks x 512 threads x 8 nodes: 8 waves/CU, weight reuse across 2
// nodes per thread, 4 independent accumulator chains.
// ---------------------------------------------------------------------------
__global__ __launch_bounds__(512) void prep_kernel(
    const float* __restrict__ bf, const float* __restrict__ emb,
    const float* __restrict__ W_cls, const float* __restrict__ b_cls,
    const float* __restrict__ W_pos, const float* __restrict__ b_pos,
    const float* __restrict__ W_in,  const float* __restrict__ b_in,
    const float* __restrict__ W_out, const float* __restrict__ b_out,
    const float* __restrict__ W_e1,  const float* __restrict__ b_e1,
    float* __restrict__ Uo, float* __restrict__ Vo)
{
    __shared__ float sbf[8][64];
    __shared__ float sft[8][64];
    __shared__ float su[8][128];
    __shared__ float sv[8][128];
    __shared__ float sp[8][2];

    const int tid   = threadIdx.x;
    const int node0 = blockIdx.x * 8;

    // stage inputs: 512 floats, one per thread
    sbf[tid >> 6][tid & 63] = bf[node0 * 64 + tid];
    if (tid < 8) {
        int g = node0 + tid;
        float ang = emb[g * 2] * PI_F;
        float t = tanf(ang);
        float rc = (emb[g * 2 + 1] * 800.0f) / cosf(ang);
        sp[tid][0] = (-t * Y0_F + rc) * INV_W;
        sp[tid][1] = (-t * Y1_F + rc) * INV_W;
    }
    __syncthreads();

    // Stage 1: feats = relu(bf @ W_cls + b_cls); one (node,h) per thread
    {
        const int nd = tid >> 6, h = tid & 63;
        float a0 = 0.f, a1 = 0.f;
        #pragma unroll 8
        for (int d = 0; d < 64; d += 2) {
            a0 += sbf[nd][d]     * W_cls[d * 64 + h];
            a1 += sbf[nd][d + 1] * W_cls[(d + 1) * 64 + h];
        }
        sft[nd][h] = fmaxf(a0 + a1 + b_cls[h], 0.0f);
    }
    __syncthreads();

    // Stage 2: u,v; thread owns k for 2 nodes (weight loaded once, 4 chains)
    {
        const int k = tid & 127, ng = tid >> 7;     // ng in 0..3
        const int n0 = ng * 2, n1 = n0 + 1;
        float au0 = 0.f, av0 = 0.f, au1 = 0.f, av1 = 0.f;
        #pragma unroll 4
        for (int h = 0; h < 64; ++h) {
            float wi = W_in [h * 128 + k];
            float wo = W_out[h * 128 + k];
            float f0 = sft[n0][h], f1 = sft[n1][h];
            au0 += f0 * wi;  av0 += f0 * wo;
            au1 += f1 * wi;  av1 += f1 * wo;
        }
        float wp0 = W_pos[k], wp1 = W_pos[128 + k];
        float pe0 = sp[n0][0] * wp0 + sp[n0][1] * wp1;
        float pe1 = sp[n1][0] * wp0 + sp[n1][1] * wp1;
        float bi = b_in[k] + b_pos[k], bo = b_out[k];
        su[n0][k] = au0 + bi + pe0;  sv[n0][k] = av0 + bo + pe0;
        su[n1][k] = au1 + bi + pe1;  sv[n1][k] = av1 + bo + pe1;
    }
    __syncthreads();

    // Stage 3: U = u@W_e1 + b_e1 ; V = v@W_e1; same mapping, 4 chains
    {
        const int k = tid & 127, ng = tid >> 7;
        const int n0 = ng * 2, n1 = n0 + 1;
        float aU0 = 0.f, aV0 = 0.f, aU1 = 0.f, aV1 = 0.f;
        #pragma unroll 4
        for (int m = 0; m < 128; ++m) {
            float w = W_e1[m * 128 + k];
            aU0 += su[n0][m] * w;  aV0 += sv[n0][m] * w;
            aU1 += su[n1][m] * w;  aV1 += sv[n1][m] * w;
        }
        float be = b_e1[k];
        Uo[(node0 + n0) * 128 + k] = aU0 + be;
        Vo[(node0 + n0) * 128 + k] = aV0;
        Uo[(node0 + n1) * 128 + k] = aU1 + be;
        Vo[(node0 + n1) * 128 + k] = aV1;
    }
}

// ---------------------------------------------------------------------------
// Kernel B: ONE WAVE PER COLUMN (64-thread blocks, 2048 blocks, ALL resident
// simultaneously; zero barriers; wave-synchronous LDS).
// Phase 0: preload all mask inputs (24 loads in flight).
// Phase 1: 8 ballot rounds compact active rows into LDS list.
// Phase 2: one row per lane per iteration, unroll-8 gathered float4s.
// Phase 3: shuffle max-reduce -> head MLP on the wave -> sigmoid.
// ---------------------------------------------------------------------------
__global__ __launch_bounds__(64) void edge_kernel(
    const float* __restrict__ U, const float* __restrict__ V,
    const float* __restrict__ cls, const int* __restrict__ aid,
    const float* __restrict__ emb,
    const float* __restrict__ W_e2, const float* __restrict__ b_e2,
    const float* __restrict__ W_n1, const float* __restrict__ b_n1,
    const float* __restrict__ W_n2, const float* __restrict__ b_n2,
    const float* __restrict__ W_hd, const float* __restrict__ b_hd,
    float* __restrict__ out)
{
    const int col  = blockIdx.x;          // b*N + j
    const int lane = threadIdx.x;

    const float cls_j = cls[col];
    if (cls_j < 0.4f) {                   // masked column: sigmoid(-1e6) == 0
        if (lane == 0) out[col] = 0.0f;
        return;
    }

    __shared__ float Vs[128];
    __shared__ float w2s[128];
    __shared__ unsigned short list[512];
    __shared__ float n1s[64];

    Vs[lane]       = V[col * 128 + lane];
    Vs[lane + 64]  = V[col * 128 + 64 + lane];
    w2s[lane]      = W_e2[lane];
    w2s[lane + 64] = W_e2[64 + lane];

    const int   rowbase = col & ~(N - 1);    // b*N
    const float ang_j   = emb[col * 2] * PI_F;
    const int   id_j    = aid[col];
    const float be2     = b_e2[0];

    // Phase 0: preload mask inputs (independent loads, all in flight)
    float ci[8]; int ai[8]; float an[8];
    #pragma unroll
    for (int rr = 0; rr < 8; ++rr) {
        int gi = rowbase + rr * 64 + lane;
        ci[rr] = cls[gi];
        ai[rr] = aid[gi];
        an[rr] = emb[gi * 2];
    }

    // Phase 1: ballot compaction (pure ALU now)
    int cnt = 0;
    #pragma unroll
    for (int rr = 0; rr < 8; ++rr) {
        bool m = (ci[rr] > cls_j) || (ci[rr] == cls_j && ai[rr] > id_j);
        m = m && (fabsf(an[rr] * PI_F - ang_j) < 0.5f);
        unsigned long long bal = __ballot(m);
        int pre = __popcll(bal & ((1ull << lane) - 1ull));
        if (m) list[cnt + pre] = (unsigned short)(rr * 64 + lane);
        cnt += __popcll(bal);
    }

    // Phase 2: one row per lane, 4 accumulator chains (proven R3 shape)
    float wm = 0.0f;
    for (int r = lane; r < cnt; r += 64) {
        int gi = rowbase + (int)list[r];
        const float4* Up = (const float4*)(U + (size_t)gi * 128);
        float s0 = 0.f, s1 = 0.f, s2 = 0.f, s3 = 0.f;
        #pragma unroll 8
        for (int k4 = 0; k4 < 32; ++k4) {
            float4 u4 = Up[k4];
            int k = k4 * 4;
            s0 += gelu_fast(u4.x - Vs[k + 0]) * w2s[k + 0];
            s1 += gelu_fast(u4.y - Vs[k + 1]) * w2s[k + 1];
            s2 += gelu_fast(u4.z - Vs[k + 2]) * w2s[k + 2];
            s3 += gelu_fast(u4.w - Vs[k + 3]) * w2s[k + 3];
        }
        wm = fmaxf(wm, ((s0 + s1) + (s2 + s3)) + be2);
    }

    // Phase 3: wave max-reduce + head MLP (wave-synchronous LDS)
    #pragma unroll
    for (int off = 32; off > 0; off >>= 1)
        wm = fmaxf(wm, __shfl_down(wm, off));
    const float nm = __shfl(wm, 0);

    n1s[lane] = fmaxf(nm * W_n1[lane] + b_n1[lane], 0.0f);
    float a = b_n2[lane];
    #pragma unroll 8
    for (int m2 = 0; m2 < 64; ++m2) a += n1s[m2] * W_n2[m2 * 64 + lane];
    a = fmaxf(a, 0.0f);
    float p = a * W_hd[lane];
    #pragma unroll
    for (int off = 32; off > 0; off >>= 1) p += __shfl_down(p, off);
    if (lane == 0) {
        float logit = p + b_hd[0];
        out[col] = 1.0f / (1.0f + expf(-logit));
    }
}

extern "C" void kernel_launch(void* const* d_in, const int* in_sizes, int n_in,
                              void* d_out, int out_size, void* d_ws, size_t ws_size,
                              hipStream_t stream) {
    const float* bf    = (const float*)d_in[0];
    const float* cls   = (const float*)d_in[1];
    const int*   aid   = (const int*)  d_in[2];
    const float* emb   = (const float*)d_in[3];
    const float* W_cls = (const float*)d_in[4];
    const float* b_cls = (const float*)d_in[5];
    const float* W_pos = (const float*)d_in[6];
    const float* b_pos = (const float*)d_in[7];
    const float* W_in  = (const float*)d_in[8];
    const float* b_in  = (const float*)d_in[9];
    const float* W_out = (const float*)d_in[10];
    const float* b_out = (const float*)d_in[11];
    const float* W_e1  = (const float*)d_in[12];
    const float* b_e1  = (const float*)d_in[13];
    const float* W_e2  = (const float*)d_in[14];
    const float* b_e2  = (const float*)d_in[15];
    const float* W_n1  = (const float*)d_in[16];
    const float* b_n1  = (const float*)d_in[17];
    const float* W_n2  = (const float*)d_in[18];
    const float* b_n2  = (const float*)d_in[19];
    const float* W_hd  = (const float*)d_in[20];
    const float* b_hd  = (const float*)d_in[21];

    float* Uw = (float*)d_ws;            // [BN,128]
    float* Vw = Uw + BN * I;             // [BN,128]
    float* out = (float*)d_out;

    prep_kernel<<<BN / 8, 512, 0, stream>>>(
        bf, emb, W_cls, b_cls, W_pos, b_pos, W_in, b_in, W_out, b_out,
        W_e1, b_e1, Uw, Vw);
    edge_kernel<<<BN, 64, 0, stream>>>(
        Uw, Vw, cls, aid, emb, W_e2, b_e2, W_n1, b_n1, W_n2, b_n2,
        W_hd, b_hd, out);
}

// Round 6
// 136.335 us; speedup vs baseline: 1.1835x; 1.0928x over previous
//
#include <hip/hip_runtime.h>
#include <math.h>

// Problem constants (fixed by setup_inputs)
#define B  4
#define N  512
#define BN (B * N)
#define H  64
#define I  128

#define PI_F   3.14159265358979323846f
#define Y0_F   160.0f
#define Y1_F   155.4930028f   // 160 - 320*(1-1e-5)/71
#define INV_W  (1.0f / 800.0f)

// Fast tanh-GELU (passed absmax 0.0 in R3/R4/R5 vs 1e-2 threshold).
__device__ __forceinline__ float gelu_fast(float x) {
    float x2 = x * x;
    float t1 = __builtin_fmaf(x2, -2.0f * 0.0356774081f, -2.0f * 0.7978845608f);
    float e  = __expf(x * t1);                       // exp(-2y)
    return x * __builtin_amdgcn_rcpf(1.0f + e);
}

// ---------------------------------------------------------------------------
// Kernel A: per-node precompute — EXACT R3 version (measured-best combo).
//   U[i] = (relu(bf_i@W_cls+b_cls)@W_in + b_in + p_i@W_pos + b_pos)@W_e1 + b_e1
//   V[j] = (relu(bf_j@W_cls+b_cls)@W_out + b_out + p_j@W_pos)@W_e1
//   edge1[b,i,j,:] = U[b,i] - V[b,j]  exactly.
// ---------------------------------------------------------------------------
#define NPB 4   // nodes per block -> 512 blocks

__global__ __launch_bounds__(256) void prep_kernel(
    const float* __restrict__ bf, const float* __restrict__ emb,
    const float* __restrict__ W_cls, const float* __restrict__ b_cls,
    const float* __restrict__ W_pos, const float* __restrict__ b_pos,
    const float* __restrict__ W_in,  const float* __restrict__ b_in,
    const float* __restrict__ W_out, const float* __restrict__ b_out,
    const float* __restrict__ W_e1,  const float* __restrict__ b_e1,
    float* __restrict__ Uo, float* __restrict__ Vo)
{
    __shared__ float sbf[NPB][64];
    __shared__ float sft[NPB][64];
    __shared__ float su[NPB][128];
    __shared__ float sv[NPB][128];
    __shared__ float sp[NPB][2];

    const int tid = threadIdx.x;
    const int node0 = blockIdx.x * NPB;

    {
        int nd = tid >> 6, d = tid & 63;
        sbf[nd][d] = bf[(node0 + nd) * 64 + d];
    }
    if (tid < NPB) {
        int g = node0 + tid;
        float ang = emb[g * 2] * PI_F;
        float t = tanf(ang);
        float rc = (emb[g * 2 + 1] * 800.0f) / cosf(ang);
        sp[tid][0] = (-t * Y0_F + rc) * INV_W;
        sp[tid][1] = (-t * Y1_F + rc) * INV_W;
    }
    __syncthreads();

    // Stage 1: feats = relu(bf @ W_cls + b_cls)   (4 acc chains)
    {
        int nd = tid >> 6, h = tid & 63;
        float a0 = 0.f, a1 = 0.f, a2 = 0.f, a3 = 0.f;
        #pragma unroll 4
        for (int d = 0; d < 64; d += 4) {
            a0 += sbf[nd][d + 0] * W_cls[(d + 0) * 64 + h];
            a1 += sbf[nd][d + 1] * W_cls[(d + 1) * 64 + h];
            a2 += sbf[nd][d + 2] * W_cls[(d + 2) * 64 + h];
            a3 += sbf[nd][d + 3] * W_cls[(d + 3) * 64 + h];
        }
        sft[nd][h] = fmaxf(b_cls[h] + ((a0 + a1) + (a2 + a3)), 0.0f);
    }
    __syncthreads();

    // Stage 2: u,v for 2 nodes per thread (weights loaded once, 4 chains)
    {
        int k = tid & 127, np = tid >> 7;     // np in {0,1}
        int n0 = np * 2, n1 = n0 + 1;
        float wp0 = W_pos[k], wp1 = W_pos[128 + k];
        float pe0 = sp[n0][0] * wp0 + sp[n0][1] * wp1;
        float pe1 = sp[n1][0] * wp0 + sp[n1][1] * wp1;
        float bi = b_in[k] + b_pos[k], bo = b_out[k];
        float au0 = 0.f, av0 = 0.f, au1 = 0.f, av1 = 0.f;
        #pragma unroll 8
        for (int h = 0; h < 64; ++h) {
            float wi = W_in[h * 128 + k];
            float wo = W_out[h * 128 + k];
            float f0 = sft[n0][h], f1 = sft[n1][h];
            au0 += f0 * wi;  av0 += f0 * wo;
            au1 += f1 * wi;  av1 += f1 * wo;
        }
        su[n0][k] = au0 + bi + pe0;  sv[n0][k] = av0 + bo + pe0;
        su[n1][k] = au1 + bi + pe1;  sv[n1][k] = av1 + bo + pe1;
    }
    __syncthreads();

    // Stage 3: U = u@W_e1 + b_e1 ; V = v@W_e1   (2 nodes/thread, 4 chains)
    {
        int k = tid & 127, np = tid >> 7;
        int n0 = np * 2, n1 = n0 + 1;
        float aU0 = 0.f, aV0 = 0.f, aU1 = 0.f, aV1 = 0.f;
        #pragma unroll 8
        for (int m = 0; m < 128; ++m) {
            float w = W_e1[m * 128 + k];
            aU0 += su[n0][m] * w;  aV0 += sv[n0][m] * w;
            aU1 += su[n1][m] * w;  aV1 += sv[n1][m] * w;
        }
        float be = b_e1[k];
        Uo[(node0 + n0) * 128 + k] = aU0 + be;
        Vo[(node0 + n0) * 128 + k] = aV0;
        Uo[(node0 + n1) * 128 + k] = aU1 + be;
        Vo[(node0 + n1) * 128 + k] = aV1;
    }
}

// ---------------------------------------------------------------------------
// Kernel B: TWO COLUMNS PER BLOCK (256 thr, 1024 blocks).
//  Phase 1: waves 0-1 mask+compact rows for col A, waves 2-3 for col B
//           (mask inputs preloaded into registers; ballot compaction).
//  Phase 2: combined item list (~2x112) distributed over ALL 256 threads ->
//           ~83% utilization; proven unroll-8 gathered-row inner loop.
//  Phase 3: dual max-reduce; head MLP on wave 0 (col A) / wave 1 (col B).
// ---------------------------------------------------------------------------
__global__ __launch_bounds__(256) void edge_kernel(
    const float* __restrict__ U, const float* __restrict__ V,
    const float* __restrict__ cls, const int* __restrict__ aid,
    const float* __restrict__ emb,
    const float* __restrict__ W_e2, const float* __restrict__ b_e2,
    const float* __restrict__ W_n1, const float* __restrict__ b_n1,
    const float* __restrict__ W_n2, const float* __restrict__ b_n2,
    const float* __restrict__ W_hd, const float* __restrict__ b_hd,
    float* __restrict__ out)
{
    const int tid  = threadIdx.x;
    const int wave = tid >> 6;
    const int lane = tid & 63;
    const int col0 = blockIdx.x * 2;          // cols col0, col0+1 (same batch)
    const int half = wave >> 1;               // which column this wave masks
    const int wsub = wave & 1;                // wave index within its half

    __shared__ float Vs[2][128];
    __shared__ float w2s[128];
    __shared__ unsigned short lseg[4][256];
    __shared__ unsigned short lists[2][512];
    __shared__ int wcnt[4];
    __shared__ float redm[2][4];
    __shared__ float n1s[2][64];

    const float clsA = cls[col0];
    const float clsB = cls[col0 + 1];
    if (clsA < 0.4f && clsB < 0.4f) {         // both masked: uniform exit
        if (tid < 2) out[col0 + tid] = 0.0f;
        return;
    }

    const int   mycol  = col0 + half;
    const float cls_j  = half ? clsB : clsA;
    const bool  active = cls_j >= 0.4f;

    if (tid < 128) w2s[tid] = W_e2[tid];
    if (wsub == 0) {                          // waves 0,2 load their V column
        Vs[half][lane]      = V[mycol * 128 + lane];
        Vs[half][lane + 64] = V[mycol * 128 + 64 + lane];
    }

    const int   rowbase = col0 & ~(N - 1);    // b*N (shared by both cols)
    const float ang_j   = emb[mycol * 2] * PI_F;
    const int   id_j    = aid[mycol];
    const float be2     = b_e2[0];

    // Phase 0+1: preload mask inputs (12 loads in flight), then ballot-compact.
    float ci[4]; int ai[4]; float an[4];
    #pragma unroll
    for (int rr = 0; rr < 4; ++rr) {
        int gi = rowbase + wsub * 256 + rr * 64 + lane;
        ci[rr] = cls[gi];
        ai[rr] = aid[gi];
        an[rr] = emb[gi * 2];
    }
    int cnt = 0;
    #pragma unroll
    for (int rr = 0; rr < 4; ++rr) {
        bool m = active &&
                 ((ci[rr] > cls_j) || (ci[rr] == cls_j && ai[rr] > id_j)) &&
                 (fabsf(an[rr] * PI_F - ang_j) < 0.5f);
        unsigned long long bal = __ballot(m);
        int pre = __popcll(bal & ((1ull << lane) - 1ull));
        if (m) lseg[wave][cnt + pre] = (unsigned short)(wsub * 256 + rr * 64 + lane);
        cnt += __popcll(bal);
    }
    if (lane == 0) wcnt[wave] = cnt;
    __syncthreads();

    const int c0 = wcnt[0], c1 = wcnt[1], c2 = wcnt[2], c3 = wcnt[3];
    const int totA = c0 + c1, totB = c2 + c3;
    for (int r = tid; r < c0; r += 256) lists[0][r]      = lseg[0][r];
    for (int r = tid; r < c1; r += 256) lists[0][c0 + r] = lseg[1][r];
    for (int r = tid; r < c2; r += 256) lists[1][r]      = lseg[2][r];
    for (int r = tid; r < c3; r += 256) lists[1][c2 + r] = lseg[3][r];
    __syncthreads();

    // Phase 2: combined items over all 256 threads; 4 accumulator chains.
    float wmA = 0.0f, wmB = 0.0f;
    const int nitems = totA + totB;
    for (int q = tid; q < nitems; q += 256) {
        int h = (q >= totA) ? 1 : 0;
        int r = h ? (q - totA) : q;
        int gi = rowbase + (int)lists[h][r];
        const float4* Up = (const float4*)(U + (size_t)gi * 128);
        const float*  Vp = Vs[h];
        float s0 = 0.f, s1 = 0.f, s2 = 0.f, s3 = 0.f;
        #pragma unroll 8
        for (int k4 = 0; k4 < 32; ++k4) {
            float4 u4 = Up[k4];
            int k = k4 * 4;
            s0 += gelu_fast(u4.x - Vp[k + 0]) * w2s[k + 0];
            s1 += gelu_fast(u4.y - Vp[k + 1]) * w2s[k + 1];
            s2 += gelu_fast(u4.z - Vp[k + 2]) * w2s[k + 2];
            s3 += gelu_fast(u4.w - Vp[k + 3]) * w2s[k + 3];
        }
        float s = ((s0 + s1) + (s2 + s3)) + be2;
        if (h) wmB = fmaxf(wmB, s); else wmA = fmaxf(wmA, s);
    }

    // Phase 3: dual max-reduce (shuffle within wave, LDS across waves)
    #pragma unroll
    for (int off = 32; off > 0; off >>= 1) {
        wmA = fmaxf(wmA, __shfl_down(wmA, off));
        wmB = fmaxf(wmB, __shfl_down(wmB, off));
    }
    if (lane == 0) { redm[0][wave] = wmA; redm[1][wave] = wmB; }
    __syncthreads();

    if (wave < 2) {                          // wave 0 -> col A, wave 1 -> col B
        const int   h    = wave;
        const int   colh = col0 + h;
        const float cj   = h ? clsB : clsA;
        if (cj >= 0.4f) {
            const float nm = fmaxf(fmaxf(redm[h][0], redm[h][1]),
                                   fmaxf(redm[h][2], redm[h][3]));
            n1s[h][lane] = fmaxf(nm * W_n1[lane] + b_n1[lane], 0.0f);
            float a = b_n2[lane];
            #pragma unroll 8
            for (int m2 = 0; m2 < 64; ++m2)
                a += n1s[h][m2] * W_n2[m2 * 64 + lane];
            a = fmaxf(a, 0.0f);
            float p = a * W_hd[lane];
            #pragma unroll
            for (int off = 32; off > 0; off >>= 1) p += __shfl_down(p, off);
            if (lane == 0) {
                float logit = p + b_hd[0];
                out[colh] = 1.0f / (1.0f + expf(-logit));
            }
        } else if (lane == 0) {
            out[colh] = 0.0f;
        }
    }
}

extern "C" void kernel_launch(void* const* d_in, const int* in_sizes, int n_in,
                              void* d_out, int out_size, void* d_ws, size_t ws_size,
                              hipStream_t stream) {
    const float* bf    = (const float*)d_in[0];
    const float* cls   = (const float*)d_in[1];
    const int*   aid   = (const int*)  d_in[2];
    const float* emb   = (const float*)d_in[3];
    const float* W_cls = (const float*)d_in[4];
    const float* b_cls = (const float*)d_in[5];
    const float* W_pos = (const float*)d_in[6];
    const float* b_pos = (const float*)d_in[7];
    const float* W_in  = (const float*)d_in[8];
    const float* b_in  = (const float*)d_in[9];
    const float* W_out = (const float*)d_in[10];
    const float* b_out = (const float*)d_in[11];
    const float* W_e1  = (const float*)d_in[12];
    const float* b_e1  = (const float*)d_in[13];
    const float* W_e2  = (const float*)d_in[14];
    const float* b_e2  = (const float*)d_in[15];
    const float* W_n1  = (const float*)d_in[16];
    const float* b_n1  = (const float*)d_in[17];
    const float* W_n2  = (const float*)d_in[18];
    const float* b_n2  = (const float*)d_in[19];
    const float* W_hd  = (const float*)d_in[20];
    const float* b_hd  = (const float*)d_in[21];

    float* Uw = (float*)d_ws;            // [BN,128]
    float* Vw = Uw + BN * I;             // [BN,128]
    float* out = (float*)d_out;

    prep_kernel<<<BN / NPB, 256, 0, stream>>>(
        bf, emb, W_cls, b_cls, W_pos, b_pos, W_in, b_in, W_out, b_out,
        W_e1, b_e1, Uw, Vw);
    edge_kernel<<<BN / 2, 256, 0, stream>>>(
        Uw, Vw, cls, aid, emb, W_e2, b_e2, W_n1, b_n1, W_n2, b_n2,
        W_hd, b_hd, out);
}

// Round 7
// 131.627 us; speedup vs baseline: 1.2258x; 1.0358x over previous
//
#include <hip/hip_runtime.h>
#include <math.h>

// Problem constants (fixed by setup_inputs)
#define B  4
#define N  512
#define BN (B * N)
#define H  64
#define I  128

#define PI_F   3.14159265358979323846f
#define Y0_F   160.0f
#define Y1_F   155.4930028f   // 160 - 320*(1-1e-5)/71
#define INV_W  (1.0f / 800.0f)

// Fast tanh-GELU (passed absmax 0.0 in R3-R6 vs 1e-2 threshold).
__device__ __forceinline__ float gelu_fast(float x) {
    float x2 = x * x;
    float t1 = __builtin_fmaf(x2, -2.0f * 0.0356774081f, -2.0f * 0.7978845608f);
    float e  = __expf(x * t1);                       // exp(-2y)
    return x * __builtin_amdgcn_rcpf(1.0f + e);
}

// ---------------------------------------------------------------------------
// Kernel A: per-node precompute — EXACT R3 version (measured-best).
//   U[i] = (relu(bf_i@W_cls+b_cls)@W_in + b_in + p_i@W_pos + b_pos)@W_e1 + b_e1
//   V[j] = (relu(bf_j@W_cls+b_cls)@W_out + b_out + p_j@W_pos)@W_e1
//   edge1[b,i,j,:] = U[b,i] - V[b,j]  exactly.
// ---------------------------------------------------------------------------
#define NPB 4   // nodes per block -> 512 blocks

__global__ __launch_bounds__(256) void prep_kernel(
    const float* __restrict__ bf, const float* __restrict__ emb,
    const float* __restrict__ W_cls, const float* __restrict__ b_cls,
    const float* __restrict__ W_pos, const float* __restrict__ b_pos,
    const float* __restrict__ W_in,  const float* __restrict__ b_in,
    const float* __restrict__ W_out, const float* __restrict__ b_out,
    const float* __restrict__ W_e1,  const float* __restrict__ b_e1,
    float* __restrict__ Uo, float* __restrict__ Vo)
{
    __shared__ float sbf[NPB][64];
    __shared__ float sft[NPB][64];
    __shared__ float su[NPB][128];
    __shared__ float sv[NPB][128];
    __shared__ float sp[NPB][2];

    const int tid = threadIdx.x;
    const int node0 = blockIdx.x * NPB;

    {
        int nd = tid >> 6, d = tid & 63;
        sbf[nd][d] = bf[(node0 + nd) * 64 + d];
    }
    if (tid < NPB) {
        int g = node0 + tid;
        float ang = emb[g * 2] * PI_F;
        float t = tanf(ang);
        float rc = (emb[g * 2 + 1] * 800.0f) / cosf(ang);
        sp[tid][0] = (-t * Y0_F + rc) * INV_W;
        sp[tid][1] = (-t * Y1_F + rc) * INV_W;
    }
    __syncthreads();

    // Stage 1: feats = relu(bf @ W_cls + b_cls)   (4 acc chains)
    {
        int nd = tid >> 6, h = tid & 63;
        float a0 = 0.f, a1 = 0.f, a2 = 0.f, a3 = 0.f;
        #pragma unroll 4
        for (int d = 0; d < 64; d += 4) {
            a0 += sbf[nd][d + 0] * W_cls[(d + 0) * 64 + h];
            a1 += sbf[nd][d + 1] * W_cls[(d + 1) * 64 + h];
            a2 += sbf[nd][d + 2] * W_cls[(d + 2) * 64 + h];
            a3 += sbf[nd][d + 3] * W_cls[(d + 3) * 64 + h];
        }
        sft[nd][h] = fmaxf(b_cls[h] + ((a0 + a1) + (a2 + a3)), 0.0f);
    }
    __syncthreads();

    // Stage 2: u,v for 2 nodes per thread (weights loaded once, 4 chains)
    {
        int k = tid & 127, np = tid >> 7;     // np in {0,1}
        int n0 = np * 2, n1 = n0 + 1;
        float wp0 = W_pos[k], wp1 = W_pos[128 + k];
        float pe0 = sp[n0][0] * wp0 + sp[n0][1] * wp1;
        float pe1 = sp[n1][0] * wp0 + sp[n1][1] * wp1;
        float bi = b_in[k] + b_pos[k], bo = b_out[k];
        float au0 = 0.f, av0 = 0.f, au1 = 0.f, av1 = 0.f;
        #pragma unroll 8
        for (int h = 0; h < 64; ++h) {
            float wi = W_in[h * 128 + k];
            float wo = W_out[h * 128 + k];
            float f0 = sft[n0][h], f1 = sft[n1][h];
            au0 += f0 * wi;  av0 += f0 * wo;
            au1 += f1 * wi;  av1 += f1 * wo;
        }
        su[n0][k] = au0 + bi + pe0;  sv[n0][k] = av0 + bo + pe0;
        su[n1][k] = au1 + bi + pe1;  sv[n1][k] = av1 + bo + pe1;
    }
    __syncthreads();

    // Stage 3: U = u@W_e1 + b_e1 ; V = v@W_e1   (2 nodes/thread, 4 chains)
    {
        int k = tid & 127, np = tid >> 7;
        int n0 = np * 2, n1 = n0 + 1;
        float aU0 = 0.f, aV0 = 0.f, aU1 = 0.f, aV1 = 0.f;
        #pragma unroll 8
        for (int m = 0; m < 128; ++m) {
            float w = W_e1[m * 128 + k];
            aU0 += su[n0][m] * w;  aV0 += sv[n0][m] * w;
            aU1 += su[n1][m] * w;  aV1 += sv[n1][m] * w;
        }
        float be = b_e1[k];
        Uo[(node0 + n0) * 128 + k] = aU0 + be;
        Vo[(node0 + n0) * 128 + k] = aV0;
        Uo[(node0 + n1) * 128 + k] = aU1 + be;
        Vo[(node0 + n1) * 128 + k] = aV1;
    }
}

// ---------------------------------------------------------------------------
// Kernel B: ONE BLOCK PER COLUMN (R3 structure) with COALESCED phase 2.
//  Phase 1: 4 waves mask 512 rows, ballot-compact, stitch into one LDS list.
//  Phase 2: each wave processes a PAIR of compacted rows per iteration:
//           lanes 0-31 load row a (32 x float4 = contiguous 512B burst),
//           lanes 32-63 load row b. 4 gelu/lane, then a 5-step shfl_xor
//           reduction confined to each 32-lane half (both rows reduce in the
//           same instructions). Coalesced: 8 line-touches/row vs 32 scattered.
//  Phase 3: max-reduce -> head MLP on wave 0 -> sigmoid.
// ---------------------------------------------------------------------------
__global__ __launch_bounds__(256) void edge_kernel(
    const float* __restrict__ U, const float* __restrict__ V,
    const float* __restrict__ cls, const int* __restrict__ aid,
    const float* __restrict__ emb,
    const float* __restrict__ W_e2, const float* __restrict__ b_e2,
    const float* __restrict__ W_n1, const float* __restrict__ b_n1,
    const float* __restrict__ W_n2, const float* __restrict__ b_n2,
    const float* __restrict__ W_hd, const float* __restrict__ b_hd,
    float* __restrict__ out)
{
    const int col  = blockIdx.x;          // b*N + j
    const int tid  = threadIdx.x;
    const int wave = tid >> 6;
    const int lane = tid & 63;

    __shared__ float Vs[128];
    __shared__ float w2s[128];
    __shared__ unsigned short lseg[4][128];
    __shared__ unsigned short list[512];
    __shared__ int wcnt[4];
    __shared__ float red[4];
    __shared__ float n1s[64];

    const float cls_j = cls[col];
    if (cls_j < 0.4f) {                   // masked column: sigmoid(-1e6) == 0
        if (tid == 0) out[col] = 0.0f;
        return;                           // uniform: whole block exits
    }

    if (tid < 128) {
        Vs[tid]  = V[col * 128 + tid];
        w2s[tid] = W_e2[tid];
    }

    const int   rowbase = col & ~(N - 1);    // b*N
    const float ang_j   = emb[col * 2] * PI_F;
    const int   id_j    = aid[col];
    const float be2     = b_e2[0];

    // Phase 1: mask + per-wave ballot compaction (each wave: 128 rows)
    int c = 0;
    #pragma unroll
    for (int rr = 0; rr < 2; ++rr) {
        int i  = wave * 128 + rr * 64 + lane;
        int gi = rowbase + i;
        float ci = cls[gi];
        bool m = (ci > cls_j) || (ci == cls_j && aid[gi] > id_j);
        if (m) m = fabsf(emb[gi * 2] * PI_F - ang_j) < 0.5f;
        unsigned long long bal = __ballot(m);
        int pre = __popcll(bal & ((1ull << lane) - 1ull));
        if (m) lseg[wave][c + pre] = (unsigned short)i;
        c += __popcll(bal);
    }
    if (lane == 0) wcnt[wave] = c;
    __syncthreads();

    const int c0 = wcnt[0], c1 = wcnt[1], c2 = wcnt[2], c3 = wcnt[3];
    const int o1 = c0, o2 = c0 + c1, o3 = o2 + c2;
    const int total = o3 + c3;
    for (int r = tid; r < c0; r += 256) list[r]      = lseg[0][r];
    for (int r = tid; r < c1; r += 256) list[o1 + r] = lseg[1][r];
    for (int r = tid; r < c2; r += 256) list[o2 + r] = lseg[2][r];
    for (int r = tid; r < c3; r += 256) list[o3 + r] = lseg[3][r];
    __syncthreads();

    // Phase 2: coalesced row-pairs. sub = which row of the pair this lane
    // serves; l5 = this lane's float4 slot within the 512B row.
    float wm = 0.0f;
    const int sub = lane >> 5;            // 0 -> row a, 1 -> row b
    const int l5  = lane & 31;
    const int npairs = (total + 1) >> 1;
    for (int p = wave; p < npairs; p += 4) {
        int ia = 2 * p;
        int ib = (ia + 1 < total) ? (ia + 1) : ia;   // odd tail: duplicate row
        int row = (int)list[sub ? ib : ia];
        const float4* Up = (const float4*)(U + (size_t)(rowbase + row) * 128) + l5;
        float4 u4 = *Up;                  // contiguous 512B burst per half-wave
        int k = l5 * 4;
        float s;
        {
            float t0 = gelu_fast(u4.x - Vs[k + 0]) * w2s[k + 0];
            float t1 = gelu_fast(u4.y - Vs[k + 1]) * w2s[k + 1];
            float t2 = gelu_fast(u4.z - Vs[k + 2]) * w2s[k + 2];
            float t3 = gelu_fast(u4.w - Vs[k + 3]) * w2s[k + 3];
            s = (t0 + t1) + (t2 + t3);
        }
        // reduce within each 32-lane half (masks 1..16 never cross halves)
        s += __shfl_xor(s, 1);
        s += __shfl_xor(s, 2);
        s += __shfl_xor(s, 4);
        s += __shfl_xor(s, 8);
        s += __shfl_xor(s, 16);
        wm = fmaxf(wm, s + be2);          // every lane holds its half's row sum
    }

    // Phase 3: max-reduce (shuffle within wave, LDS across waves)
    #pragma unroll
    for (int off = 32; off > 0; off >>= 1)
        wm = fmaxf(wm, __shfl_down(wm, off));
    if (lane == 0) red[wave] = wm;
    __syncthreads();

    if (wave == 0) {
        const float nm = fmaxf(fmaxf(red[0], red[1]), fmaxf(red[2], red[3]));
        // head MLP entirely on wave 0 (LDS in-order within a wave)
        n1s[lane] = fmaxf(nm * W_n1[lane] + b_n1[lane], 0.0f);
        float a = b_n2[lane];
        #pragma unroll 8
        for (int m2 = 0; m2 < 64; ++m2) a += n1s[m2] * W_n2[m2 * 64 + lane];
        a = fmaxf(a, 0.0f);
        float p = a * W_hd[lane];
        #pragma unroll
        for (int off = 32; off > 0; off >>= 1) p += __shfl_down(p, off);
        if (lane == 0) {
            float logit = p + b_hd[0];
            out[col] = 1.0f / (1.0f + expf(-logit));
        }
    }
}

extern "C" void kernel_launch(void* const* d_in, const int* in_sizes, int n_in,
                              void* d_out, int out_size, void* d_ws, size_t ws_size,
                              hipStream_t stream) {
    const float* bf    = (const float*)d_in[0];
    const float* cls   = (const float*)d_in[1];
    const int*   aid   = (const int*)  d_in[2];
    const float* emb   = (const float*)d_in[3];
    const float* W_cls = (const float*)d_in[4];
    const float* b_cls = (const float*)d_in[5];
    const float* W_pos = (const float*)d_in[6];
    const float* b_pos = (const float*)d_in[7];
    const float* W_in  = (const float*)d_in[8];
    const float* b_in  = (const float*)d_in[9];
    const float* W_out = (const float*)d_in[10];
    const float* b_out = (const float*)d_in[11];
    const float* W_e1  = (const float*)d_in[12];
    const float* b_e1  = (const float*)d_in[13];
    const float* W_e2  = (const float*)d_in[14];
    const float* b_e2  = (const float*)d_in[15];
    const float* W_n1  = (const float*)d_in[16];
    const float* b_n1  = (const float*)d_in[17];
    const float* W_n2  = (const float*)d_in[18];
    const float* b_n2  = (const float*)d_in[19];
    const float* W_hd  = (const float*)d_in[20];
    const float* b_hd  = (const float*)d_in[21];

    float* Uw = (float*)d_ws;            // [BN,128]
    float* Vw = Uw + BN * I;             // [BN,128]
    float* out = (float*)d_out;

    prep_kernel<<<BN / NPB, 256, 0, stream>>>(
        bf, emb, W_cls, b_cls, W_pos, b_pos, W_in, b_in, W_out, b_out,
        W_e1, b_e1, Uw, Vw);
    edge_kernel<<<BN, 256, 0, stream>>>(
        Uw, Vw, cls, aid, emb, W_e2, b_e2, W_n1, b_n1, W_n2, b_n2,
        W_hd, b_hd, out);
}

// Round 8
// 129.487 us; speedup vs baseline: 1.2461x; 1.0165x over previous
//
#include <hip/hip_runtime.h>
#include <math.h>

// Problem constants (fixed by setup_inputs)
#define B  4
#define N  512
#define BN (B * N)
#define H  64
#define I  128

#define PI_F   3.14159265358979323846f
#define Y0_F   160.0f
#define Y1_F   155.4930028f   // 160 - 320*(1-1e-5)/71
#define INV_W  (1.0f / 800.0f)

// Fast tanh-GELU (passed absmax 0.0 in R3-R7 vs 1e-2 threshold).
__device__ __forceinline__ float gelu_fast(float x) {
    float x2 = x * x;
    float t1 = __builtin_fmaf(x2, -2.0f * 0.0356774081f, -2.0f * 0.7978845608f);
    float e  = __expf(x * t1);                       // exp(-2y)
    return x * __builtin_amdgcn_rcpf(1.0f + e);
}

// ---------------------------------------------------------------------------
// Kernel A: per-node precompute — EXACT R3 version (measured-best).
//   U[i] = (relu(bf_i@W_cls+b_cls)@W_in + b_in + p_i@W_pos + b_pos)@W_e1 + b_e1
//   V[j] = (relu(bf_j@W_cls+b_cls)@W_out + b_out + p_j@W_pos)@W_e1
//   edge1[b,i,j,:] = U[b,i] - V[b,j]  exactly.
// ---------------------------------------------------------------------------
#define NPB 4   // nodes per block -> 512 blocks

__global__ __launch_bounds__(256) void prep_kernel(
    const float* __restrict__ bf, const float* __restrict__ emb,
    const float* __restrict__ W_cls, const float* __restrict__ b_cls,
    const float* __restrict__ W_pos, const float* __restrict__ b_pos,
    const float* __restrict__ W_in,  const float* __restrict__ b_in,
    const float* __restrict__ W_out, const float* __restrict__ b_out,
    const float* __restrict__ W_e1,  const float* __restrict__ b_e1,
    float* __restrict__ Uo, float* __restrict__ Vo)
{
    __shared__ float sbf[NPB][64];
    __shared__ float sft[NPB][64];
    __shared__ float su[NPB][128];
    __shared__ float sv[NPB][128];
    __shared__ float sp[NPB][2];

    const int tid = threadIdx.x;
    const int node0 = blockIdx.x * NPB;

    {
        int nd = tid >> 6, d = tid & 63;
        sbf[nd][d] = bf[(node0 + nd) * 64 + d];
    }
    if (tid < NPB) {
        int g = node0 + tid;
        float ang = emb[g * 2] * PI_F;
        float t = tanf(ang);
        float rc = (emb[g * 2 + 1] * 800.0f) / cosf(ang);
        sp[tid][0] = (-t * Y0_F + rc) * INV_W;
        sp[tid][1] = (-t * Y1_F + rc) * INV_W;
    }
    __syncthreads();

    // Stage 1: feats = relu(bf @ W_cls + b_cls)   (4 acc chains)
    {
        int nd = tid >> 6, h = tid & 63;
        float a0 = 0.f, a1 = 0.f, a2 = 0.f, a3 = 0.f;
        #pragma unroll 4
        for (int d = 0; d < 64; d += 4) {
            a0 += sbf[nd][d + 0] * W_cls[(d + 0) * 64 + h];
            a1 += sbf[nd][d + 1] * W_cls[(d + 1) * 64 + h];
            a2 += sbf[nd][d + 2] * W_cls[(d + 2) * 64 + h];
            a3 += sbf[nd][d + 3] * W_cls[(d + 3) * 64 + h];
        }
        sft[nd][h] = fmaxf(b_cls[h] + ((a0 + a1) + (a2 + a3)), 0.0f);
    }
    __syncthreads();

    // Stage 2: u,v for 2 nodes per thread (weights loaded once, 4 chains)
    {
        int k = tid & 127, np = tid >> 7;     // np in {0,1}
        int n0 = np * 2, n1 = n0 + 1;
        float wp0 = W_pos[k], wp1 = W_pos[128 + k];
        float pe0 = sp[n0][0] * wp0 + sp[n0][1] * wp1;
        float pe1 = sp[n1][0] * wp0 + sp[n1][1] * wp1;
        float bi = b_in[k] + b_pos[k], bo = b_out[k];
        float au0 = 0.f, av0 = 0.f, au1 = 0.f, av1 = 0.f;
        #pragma unroll 8
        for (int h = 0; h < 64; ++h) {
            float wi = W_in[h * 128 + k];
            float wo = W_out[h * 128 + k];
            float f0 = sft[n0][h], f1 = sft[n1][h];
            au0 += f0 * wi;  av0 += f0 * wo;
            au1 += f1 * wi;  av1 += f1 * wo;
        }
        su[n0][k] = au0 + bi + pe0;  sv[n0][k] = av0 + bo + pe0;
        su[n1][k] = au1 + bi + pe1;  sv[n1][k] = av1 + bo + pe1;
    }
    __syncthreads();

    // Stage 3: U = u@W_e1 + b_e1 ; V = v@W_e1   (2 nodes/thread, 4 chains)
    {
        int k = tid & 127, np = tid >> 7;
        int n0 = np * 2, n1 = n0 + 1;
        float aU0 = 0.f, aV0 = 0.f, aU1 = 0.f, aV1 = 0.f;
        #pragma unroll 8
        for (int m = 0; m < 128; ++m) {
            float w = W_e1[m * 128 + k];
            aU0 += su[n0][m] * w;  aV0 += sv[n0][m] * w;
            aU1 += su[n1][m] * w;  aV1 += sv[n1][m] * w;
        }
        float be = b_e1[k];
        Uo[(node0 + n0) * 128 + k] = aU0 + be;
        Vo[(node0 + n0) * 128 + k] = aV0;
        Uo[(node0 + n1) * 128 + k] = aU1 + be;
        Vo[(node0 + n1) * 128 + k] = aV1;
    }
}

// ---------------------------------------------------------------------------
// Kernel B: ONE BLOCK PER COLUMN, coalesced pair phase 2 (R7) +
//  - V-slice and W_e2-slice hoisted to REGISTERS (loop-invariant per lane),
//    loaded straight from global — no LDS traffic for them, no setup barrier
//    dependency.
//  - All column-level loads issued BEFORE the early-exit branch so active
//    blocks overlap the cls_j -> branch -> V chain.
// ---------------------------------------------------------------------------
__global__ __launch_bounds__(256) void edge_kernel(
    const float* __restrict__ U, const float* __restrict__ V,
    const float* __restrict__ cls, const int* __restrict__ aid,
    const float* __restrict__ emb,
    const float* __restrict__ W_e2, const float* __restrict__ b_e2,
    const float* __restrict__ W_n1, const float* __restrict__ b_n1,
    const float* __restrict__ W_n2, const float* __restrict__ b_n2,
    const float* __restrict__ W_hd, const float* __restrict__ b_hd,
    float* __restrict__ out)
{
    const int col  = blockIdx.x;          // b*N + j
    const int tid  = threadIdx.x;
    const int wave = tid >> 6;
    const int lane = tid & 63;
    const int l5   = lane & 31;           // float4 slot within the 512B row
    const int sub  = lane >> 5;           // 0 -> row a, 1 -> row b

    __shared__ unsigned short lseg[4][128];
    __shared__ unsigned short list[512];
    __shared__ int wcnt[4];
    __shared__ float red[4];
    __shared__ float n1s[64];

    // ---- speculative column-level loads (issued before branch resolves) ----
    const float  cls_j = cls[col];
    const float4 v4    = *((const float4*)(V + (size_t)col * 128) + l5);
    const float4 w4    = *((const float4*)W_e2 + l5);
    const float  be2   = b_e2[0];
    const float  ang_j = emb[col * 2] * PI_F;
    const int    id_j  = aid[col];

    if (cls_j < 0.4f) {                   // masked column: sigmoid(-1e6) == 0
        if (tid == 0) out[col] = 0.0f;
        return;                           // uniform: whole block exits
    }

    const int rowbase = col & ~(N - 1);   // b*N

    // Phase 1: preload mask inputs, then ballot compaction (128 rows/wave)
    float ci[2]; int ai[2]; float an[2];
    #pragma unroll
    for (int rr = 0; rr < 2; ++rr) {
        int gi = rowbase + wave * 128 + rr * 64 + lane;
        ci[rr] = cls[gi];
        ai[rr] = aid[gi];
        an[rr] = emb[gi * 2];
    }
    int c = 0;
    #pragma unroll
    for (int rr = 0; rr < 2; ++rr) {
        bool m = (ci[rr] > cls_j) || (ci[rr] == cls_j && ai[rr] > id_j);
        m = m && (fabsf(an[rr] * PI_F - ang_j) < 0.5f);
        unsigned long long bal = __ballot(m);
        int pre = __popcll(bal & ((1ull << lane) - 1ull));
        if (m) lseg[wave][c + pre] = (unsigned short)(wave * 128 + rr * 64 + lane);
        c += __popcll(bal);
    }
    if (lane == 0) wcnt[wave] = c;
    __syncthreads();

    const int c0 = wcnt[0], c1 = wcnt[1], c2 = wcnt[2], c3 = wcnt[3];
    const int o1 = c0, o2 = c0 + c1, o3 = o2 + c2;
    const int total = o3 + c3;
    for (int r = tid; r < c0; r += 256) list[r]      = lseg[0][r];
    for (int r = tid; r < c1; r += 256) list[o1 + r] = lseg[1][r];
    for (int r = tid; r < c2; r += 256) list[o2 + r] = lseg[2][r];
    for (int r = tid; r < c3; r += 256) list[o3 + r] = lseg[3][r];
    __syncthreads();

    // Phase 2: coalesced row pairs; V/w2 slices live in registers.
    float wm = 0.0f;
    const int npairs = (total + 1) >> 1;
    for (int p = wave; p < npairs; p += 4) {
        int ia = 2 * p;
        int ib = (ia + 1 < total) ? (ia + 1) : ia;   // odd tail: duplicate row
        int row = (int)list[sub ? ib : ia];
        float4 u4 = *((const float4*)(U + (size_t)(rowbase + row) * 128) + l5);
        float t0 = gelu_fast(u4.x - v4.x) * w4.x;
        float t1 = gelu_fast(u4.y - v4.y) * w4.y;
        float t2 = gelu_fast(u4.z - v4.z) * w4.z;
        float t3 = gelu_fast(u4.w - v4.w) * w4.w;
        float s = (t0 + t1) + (t2 + t3);
        // reduce within each 32-lane half (masks 1..16 never cross halves)
        s += __shfl_xor(s, 1);
        s += __shfl_xor(s, 2);
        s += __shfl_xor(s, 4);
        s += __shfl_xor(s, 8);
        s += __shfl_xor(s, 16);
        wm = fmaxf(wm, s + be2);          // every lane holds its half's row sum
    }

    // Phase 3: max-reduce (shuffle within wave, LDS across waves)
    #pragma unroll
    for (int off = 32; off > 0; off >>= 1)
        wm = fmaxf(wm, __shfl_down(wm, off));
    if (lane == 0) red[wave] = wm;
    __syncthreads();

    if (wave == 0) {
        const float nm = fmaxf(fmaxf(red[0], red[1]), fmaxf(red[2], red[3]));
        // head MLP entirely on wave 0 (LDS in-order within a wave)
        n1s[lane] = fmaxf(nm * W_n1[lane] + b_n1[lane], 0.0f);
        float a = b_n2[lane];
        #pragma unroll 8
        for (int m2 = 0; m2 < 64; ++m2) a += n1s[m2] * W_n2[m2 * 64 + lane];
        a = fmaxf(a, 0.0f);
        float p = a * W_hd[lane];
        #pragma unroll
        for (int off = 32; off > 0; off >>= 1) p += __shfl_down(p, off);
        if (lane == 0) {
            float logit = p + b_hd[0];
            out[col] = 1.0f / (1.0f + expf(-logit));
        }
    }
}

extern "C" void kernel_launch(void* const* d_in, const int* in_sizes, int n_in,
                              void* d_out, int out_size, void* d_ws, size_t ws_size,
                              hipStream_t stream) {
    const float* bf    = (const float*)d_in[0];
    const float* cls   = (const float*)d_in[1];
    const int*   aid   = (const int*)  d_in[2];
    const float* emb   = (const float*)d_in[3];
    const float* W_cls = (const float*)d_in[4];
    const float* b_cls = (const float*)d_in[5];
    const float* W_pos = (const float*)d_in[6];
    const float* b_pos = (const float*)d_in[7];
    const float* W_in  = (const float*)d_in[8];
    const float* b_in  = (const float*)d_in[9];
    const float* W_out = (const float*)d_in[10];
    const float* b_out = (const float*)d_in[11];
    const float* W_e1  = (const float*)d_in[12];
    const float* b_e1  = (const float*)d_in[13];
    const float* W_e2  = (const float*)d_in[14];
    const float* b_e2  = (const float*)d_in[15];
    const float* W_n1  = (const float*)d_in[16];
    const float* b_n1  = (const float*)d_in[17];
    const float* W_n2  = (const float*)d_in[18];
    const float* b_n2  = (const float*)d_in[19];
    const float* W_hd  = (const float*)d_in[20];
    const float* b_hd  = (const float*)d_in[21];

    float* Uw = (float*)d_ws;            // [BN,128]
    float* Vw = Uw + BN * I;             // [BN,128]
    float* out = (float*)d_out;

    prep_kernel<<<BN / NPB, 256, 0, stream>>>(
        bf, emb, W_cls, b_cls, W_pos, b_pos, W_in, b_in, W_out, b_out,
        W_e1, b_e1, Uw, Vw);
    edge_kernel<<<BN, 256, 0, stream>>>(
        Uw, Vw, cls, aid, emb, W_e2, b_e2, W_n1, b_n1, W_n2, b_n2,
        W_hd, b_hd, out);
}